// Round 19
// baseline (417.089 us; speedup 1.0000x reference)
//
#include <hip/hip_runtime.h>

// LIF sim, three-phase:
//   0) split_h: pre-split h1 into bf16 hi/lo planes in d_ws ([kt][nb] 16KB
//      chunks == the gemm's swizzled B-LDS image, BN=256).
//   1) lif_gemm<true>: aS = X @ H via bf16 3-product-split MFMA.
//      BM=128 x BN=256, 512 threads (8 waves 2m x 4n): A-conversion
//      redundancy halved vs 128x128, B L2 traffic unchanged, 3 blocks/CU.
//      Per-wave tile & MFMA order identical to R16 -> bit-identical aS.
//   2) lif_scan: R16 verbatim — speculative 8-step dense batches w/ rollback.
typedef __attribute__((ext_vector_type(8))) short short8;
typedef __attribute__((ext_vector_type(4))) float f32x4;

constexpr int BSZ = 256;
constexpr int NRN = 512;
constexpr int KIN = 512;
constexpr int TT  = 500;
constexpr int BM  = 128;   // m-tile
constexpr int BN  = 256;   // n-tile
constexpr int KT  = 32;    // k-tile
constexpr int NBLK = (TT * BSZ / BM) * (NRN / BN);   // 1000 * 2 = 2000
constexpr size_t WS_NEED = (size_t)2 * KIN * NRN * sizeof(unsigned short); // 1 MB
constexpr unsigned long long FULLM = 0xFFFFFFFFFFFFFFFFULL;

__device__ __forceinline__ unsigned short bf16rne(float f) {
    unsigned u = __float_as_uint(f);
    u += 0x7FFFu + ((u >> 16) & 1u);
    return (unsigned short)(u >> 16);
}
__device__ __forceinline__ float bf16f(unsigned short s) {
    return __uint_as_float(((unsigned)s) << 16);
}
// packed RNE bf16 pair: low16 = bf16(a), high16 = bf16(b). Bit-identical to bf16rne.
__device__ __forceinline__ unsigned cvtpk(float a, float b) {
    unsigned r;
    asm("v_cvt_pk_bf16_f32 %0, %1, %2" : "=v"(r) : "v"(a), "v"(b));
    return r;
}

// h1[k][n] -> hi/lo bf16 planes, laid out as the gemm's B-LDS image:
// chunk (kt*2+nb) of 16384 B; byte = ((nl*64+koct*16) ^ (((nl>>1)&3)<<4)) + 2*i
__global__ __launch_bounds__(512)
void split_h(const float* __restrict__ h1,
             unsigned short* __restrict__ wsH,
             unsigned short* __restrict__ wsL)
{
    const int k = blockIdx.x;          // 0..511
    const int n = threadIdx.x;         // 0..511 (coalesced read)
    const float v = h1[(size_t)k * NRN + n];
    const unsigned short h  = bf16rne(v);
    const unsigned short lo = bf16rne(v - bf16f(h));
    const int kt = k >> 5, koct = (k >> 3) & 3, i = k & 7;
    const int nb = n >> 8, nl = n & 255;
    const int byte = (kt * 2 + nb) * 16384 +
                     ((nl * 64 + koct * 16) ^ (((nl >> 1) & 3) << 4)) + i * 2;
    *reinterpret_cast<unsigned short*>((char*)wsH + byte) = h;
    *reinterpret_cast<unsigned short*>((char*)wsL + byte) = lo;
}

template<bool PS>
__global__ __launch_bounds__(512)
void lif_gemm(const float* __restrict__ x,
              const float* __restrict__ h1,
              const unsigned short* __restrict__ wsH,
              const unsigned short* __restrict__ wsL,
              float* __restrict__ out)
{
    // bf16 tiles, XOR-swizzled (byte ^= ((row>>1)&3)<<4):
    // A 2x8KB + B 2x16KB = 48 KB -> 3 blocks/CU
    __shared__ short AhS[BM * KT], AlS[BM * KT], BhS[BN * KT], BlS[BN * KT];

    const int tid  = threadIdx.x;        // 0..511
    const int l    = tid & 63;
    const int w    = tid >> 6;           // wave 0..7
    const int wm   = (w & 1) * 64;       // wave m-offset (2 m-groups)
    const int wn   = (w >> 1) * 64;      // wave n-offset (4 n-groups: 0..192)
    const int lrow = l & 15;
    const int loct = l >> 4;             // k-octet 0..3

    // XCD-chunked bijective swizzle: 2000 = 8 x 250; 250 % 2 == 0 so both
    // n-blocks of each m-tile stay inside one XCD's chunk (shared L2).
    const int nid = (blockIdx.x & 7) * (NBLK / 8) + (blockIdx.x >> 3);
    const size_t m0 = (size_t)(nid >> 1) * BM;
    const int    nb = nid & 1;
    const int    n0 = nb * BN;

    f32x4 acc[4][4];
    #pragma unroll
    for (int i = 0; i < 4; ++i)
        #pragma unroll
        for (int j = 0; j < 4; ++j) acc[i][j] = (f32x4)0.0f;

    for (int kt = 0; kt < KIN / KT; ++kt) {
        // ---- stage B (independent loads issue first, overlap A conversion) ----
        if (PS) {
            // linear conflict-free copy: 16B/lane consecutive, 16KB per plane
            const float4* sH = reinterpret_cast<const float4*>(
                (const char*)wsH + (kt * 2 + nb) * 16384);
            const float4* sL = reinterpret_cast<const float4*>(
                (const char*)wsL + (kt * 2 + nb) * 16384);
            float4* dH = reinterpret_cast<float4*>(BhS);
            float4* dL = reinterpret_cast<float4*>(BlS);
            dH[tid]       = sH[tid];
            dH[512 + tid] = sH[512 + tid];
            dL[tid]       = sL[tid];
            dL[512 + tid] = sL[512 + tid];
        } else {
            #pragma unroll
            for (int u2 = 0; u2 < 2; ++u2) {
                const int u = u2 * 512 + tid;          // 0..1023
                const int nl = u & 255, koct = u >> 8; // n-local, k-octet
                short8 hh, hl;
                #pragma unroll
                for (int i = 0; i < 8; ++i) {          // coalesced across nl
                    const float v = h1[(size_t)(kt * KT + koct * 8 + i) * NRN + n0 + nl];
                    const unsigned short h = bf16rne(v);
                    hh[i] = (short)h;
                    hl[i] = (short)bf16rne(v - bf16f(h));
                }
                const int byte = (nl * 64 + koct * 16) ^ (((nl >> 1) & 3) << 4);
                *reinterpret_cast<short8*>((char*)BhS + byte) = hh;
                *reinterpret_cast<short8*>((char*)BlS + byte) = hl;
            }
        }
        // ---- stage A: x[m0..m0+128][kt*32..+32] -> bf16 split via cvt_pk ----
        #pragma unroll
        for (int u2 = 0; u2 < 2; ++u2) {
            const int idx = u2 * 512 + tid;         // 0..1023
            const int row = idx >> 3, slot = idx & 7; // row 0..127, float4 slot
            const float4 xv = *reinterpret_cast<const float4*>(
                x + (m0 + row) * KIN + kt * KT + slot * 4);
            // hi plane (RNE, bit-identical to bf16rne)
            const unsigned h01 = cvtpk(xv.x, xv.y);
            const unsigned h23 = cvtpk(xv.z, xv.w);
            // residuals: bf16f(lo16)=bits<<16, bf16f(hi16)=bits&0xFFFF0000
            const float r0  = xv.x - __uint_as_float(h01 << 16);
            const float r1v = xv.y - __uint_as_float(h01 & 0xFFFF0000u);
            const float r2  = xv.z - __uint_as_float(h23 << 16);
            const float r3  = xv.w - __uint_as_float(h23 & 0xFFFF0000u);
            const unsigned l01 = cvtpk(r0, r1v);
            const unsigned l23 = cvtpk(r2, r3);
            const unsigned long long hb = (unsigned long long)h01 | ((unsigned long long)h23 << 32);
            const unsigned long long lb = (unsigned long long)l01 | ((unsigned long long)l23 << 32);
            const int byte = (row * 64 + slot * 8) ^ (((row >> 1) & 3) << 4);
            *reinterpret_cast<unsigned long long*>((char*)AhS + byte) = hb;
            *reinterpret_cast<unsigned long long*>((char*)AlS + byte) = lb;
        }
        __syncthreads();

        // ---- fragment loads (ds_read_b128) ----
        short8 ah[4], al[4], bh[4], bl[4];
        #pragma unroll
        for (int mi = 0; mi < 4; ++mi) {
            const int row  = wm + mi * 16 + lrow;
            const int byte = (row * 64 + loct * 16) ^ (((row >> 1) & 3) << 4);
            ah[mi] = *reinterpret_cast<const short8*>((const char*)AhS + byte);
            al[mi] = *reinterpret_cast<const short8*>((const char*)AlS + byte);
        }
        #pragma unroll
        for (int ni = 0; ni < 4; ++ni) {
            const int nn   = wn + ni * 16 + lrow;          // 0..255
            const int byte = (nn * 64 + loct * 16) ^ (((nn >> 1) & 3) << 4);
            bh[ni] = *reinterpret_cast<const short8*>((const char*)BhS + byte);
            bl[ni] = *reinterpret_cast<const short8*>((const char*)BlS + byte);
        }

        // ---- 48 MFMA: 3-product split (xl·hl dropped, ~1e-4 class) ----
        __builtin_amdgcn_s_setprio(1);
        #pragma unroll
        for (int mi = 0; mi < 4; ++mi)
            #pragma unroll
            for (int ni = 0; ni < 4; ++ni) {
                acc[mi][ni] = __builtin_amdgcn_mfma_f32_16x16x32_bf16(ah[mi], bh[ni], acc[mi][ni], 0, 0, 0);
                acc[mi][ni] = __builtin_amdgcn_mfma_f32_16x16x32_bf16(ah[mi], bl[ni], acc[mi][ni], 0, 0, 0);
                acc[mi][ni] = __builtin_amdgcn_mfma_f32_16x16x32_bf16(al[mi], bh[ni], acc[mi][ni], 0, 0, 0);
            }
        __builtin_amdgcn_s_setprio(0);
        __syncthreads();
    }

    // ---- epilogue: C/D layout col=lane&15, row=(lane>>4)*4+j (m89-verified) ----
    #pragma unroll
    for (int mi = 0; mi < 4; ++mi)
        #pragma unroll
        for (int j = 0; j < 4; ++j) {
            const size_t row = m0 + wm + mi * 16 + loct * 4 + j;
            float* op = out + row * NRN + n0 + wn + lrow;
            #pragma unroll
            for (int ni = 0; ni < 4; ++ni)
                op[ni * 16] = acc[mi][ni][j];
        }
}

__global__ __launch_bounds__(512, 2)
void lif_scan(const float* __restrict__ r1,
              float* __restrict__ out)
{
    __shared__ unsigned long long smask[2][8];   // ping-pong 512-bit spike mask
    __shared__ unsigned long long flg[2];        // per-wave class bytes
    __shared__ unsigned long long vflg;          // batch verdict bytes

    const int n  = threadIdx.x;      // neuron
    const int b  = blockIdx.x;       // batch row
    const int wv = n >> 6;
    const int ln = n & 63;
    const size_t row = (size_t)b * NRN + n;
    constexpr size_t STEP = (size_t)BSZ * NRN;

    if (n < 16) ((unsigned long long*)smask)[n] = 0ULL;
    if (n < 2)  flg[n] = 0ULL;

    // f64 ascending-j column sum of r1 (dense recurrent fast path)
    double csum = 0.0;
    for (int j = 0; j < KIN; ++j)
        csum += (double)r1[(size_t)j * NRN + n];

    double V = 1.0, Is = 0.0, Ir = 0.0, cnt = 0.0;
    const double steady = 0.01 * (double)n;
    constexpr double kS = 0.1, kN = 0.05, DT = 0.001;

    float cur[8], nxt[8];
    #pragma unroll
    for (int i = 0; i < 8; ++i) cur[i] = out[(size_t)i * STEP + row];
    __syncthreads();

#define STD_STEP(T, AREG)                                                     \
    {                                                                         \
        const int t_ = (T);                                                   \
        const int p_ = t_ & 1;                                                \
        const unsigned long long f_ = flg[p_];                                \
        double aR;                                                            \
        if (f_ == FULLM) {                                                    \
            aR = csum;                                                        \
        } else if (f_ == 0ULL) {                                              \
            aR = 0.0;                                                         \
        } else {                                                              \
            aR = 0.0;                                                         \
            _Pragma("unroll")                                                 \
            for (int w = 0; w < 8; ++w) {                                     \
                unsigned long long m_ = smask[p_][w];                         \
                while (m_) {                          /* ascending j */       \
                    const int j = w * 64 + __builtin_ctzll(m_);               \
                    aR += (double)r1[(size_t)j * NRN + n];                    \
                    m_ &= m_ - 1;                                             \
                }                                                             \
            }                                                                 \
        }                                                                     \
        Is = Is - kS * Is + (double)(AREG);            /* gain_syn = 1 */     \
        Ir = Ir - kS * Ir + 0.5 * aR;                  /* gain_syn_rec */     \
        double Vn = V - kN * V + DT * (Is + Ir + steady);                     \
        Vn = fmax(Vn, 0.0);                                                   \
        const bool sp = (Vn - 1.0) > 0.0;                                     \
        cnt = sp ? 2.0 : (cnt - 1.0);                  /* REFR = 2 */         \
        V = sp ? 0.0 : ((cnt <= 0.0) ? Vn : 0.0);                             \
        out[(size_t)t_ * STEP + row] = sp ? 1.0f : 0.0f;                      \
        const unsigned long long bal = __ballot(sp);                          \
        if (ln == 0) {                                                        \
            smask[p_ ^ 1][wv] = bal;                                          \
            const unsigned char fb =                                          \
                (bal == FULLM) ? 0xFFu : ((bal == 0ULL) ? 0x00u : 0x01u);     \
            ((unsigned char*)&flg[p_ ^ 1])[wv] = fb;                          \
        }                                                                     \
        __syncthreads();                                                      \
    }

    for (int t0 = 0; t0 < 496; t0 += 8) {      // 62 batches of 8
        #pragma unroll
        for (int i = 0; i < 8; ++i)
            nxt[i] = (t0 + 8 + i < TT) ? out[(size_t)(t0 + 8 + i) * STEP + row] : 0.0f;

        if (flg[t0 & 1] == FULLM) {
            // ---- speculative dense batch: no barriers, aR = csum each step ----
            const double Vc = V, Isc = Is, Irc = Ir, cc = cnt;
            bool allm = true;
            #pragma unroll
            for (int i = 0; i < 8; ++i) {
                Is = Is - kS * Is + (double)cur[i];
                Ir = Ir - kS * Ir + 0.5 * csum;
                double Vn = V - kN * V + DT * (Is + Ir + steady);
                Vn = fmax(Vn, 0.0);
                const bool sp = (Vn - 1.0) > 0.0;
                allm &= sp;
                cnt = sp ? 2.0 : (cnt - 1.0);
                V = sp ? 0.0 : ((cnt <= 0.0) ? Vn : 0.0);
                out[(size_t)(t0 + i) * STEP + row] = sp ? 1.0f : 0.0f;
            }
            const unsigned long long bal = __ballot(allm);
            if (ln == 0) {
                ((unsigned char*)&vflg)[wv] = (bal == FULLM) ? 0xFFu : 0x00u;
                smask[t0 & 1][wv] = FULLM;
                ((unsigned char*)&flg[t0 & 1])[wv] = 0xFFu;
            }
            __syncthreads();
            if (vflg != FULLM) {
                V = Vc; Is = Isc; Ir = Irc; cnt = cc;
                STD_STEP(t0 + 0, cur[0])
                STD_STEP(t0 + 1, cur[1])
                STD_STEP(t0 + 2, cur[2])
                STD_STEP(t0 + 3, cur[3])
                STD_STEP(t0 + 4, cur[4])
                STD_STEP(t0 + 5, cur[5])
                STD_STEP(t0 + 6, cur[6])
                STD_STEP(t0 + 7, cur[7])
            }
        } else {
            STD_STEP(t0 + 0, cur[0])
            STD_STEP(t0 + 1, cur[1])
            STD_STEP(t0 + 2, cur[2])
            STD_STEP(t0 + 3, cur[3])
            STD_STEP(t0 + 4, cur[4])
            STD_STEP(t0 + 5, cur[5])
            STD_STEP(t0 + 6, cur[6])
            STD_STEP(t0 + 7, cur[7])
        }

        #pragma unroll
        for (int i = 0; i < 8; ++i) cur[i] = nxt[i];
    }

    STD_STEP(496, cur[0])
    STD_STEP(497, cur[1])
    STD_STEP(498, cur[2])
    STD_STEP(499, cur[3])
#undef STD_STEP
}

extern "C" void kernel_launch(void* const* d_in, const int* in_sizes, int n_in,
                              void* d_out, int out_size, void* d_ws, size_t ws_size,
                              hipStream_t stream) {
    const float* x  = (const float*)d_in[0];
    const float* h1 = (const float*)d_in[1];
    const float* r1 = (const float*)d_in[2];
    float* out = (float*)d_out;
    (void)in_sizes; (void)n_in; (void)out_size;

    if (ws_size >= WS_NEED) {
        unsigned short* wsH = (unsigned short*)d_ws;
        unsigned short* wsL = wsH + (size_t)KIN * NRN;
        split_h<<<dim3(KIN), dim3(NRN), 0, stream>>>(h1, wsH, wsL);
        lif_gemm<true><<<dim3(NBLK), dim3(512), 0, stream>>>(x, h1, wsH, wsL, out);
    } else {
        lif_gemm<false><<<dim3(NBLK), dim3(512), 0, stream>>>(x, h1, nullptr, nullptr, out);
    }
    lif_scan<<<dim3(BSZ), dim3(512), 0, stream>>>(r1, out);
}

// Round 20
// 347.051 us; speedup vs baseline: 1.2018x; 1.2018x over previous
//
#include <hip/hip_runtime.h>

// LIF sim, three-phase:
//   0) split_h: pre-split h1 into bf16 hi/lo planes in d_ws ([kt][nb] 8KB
//      chunks == the gemm's swizzled B-LDS image).        (R16 verbatim)
//   1) lif_gemm_ps: aS = X @ H via bf16 3-product-split MFMA, 128x128,
//      DOUBLE-BUFFERED LDS pipeline: stage k+1 global loads issued inside
//      k's MFMA phase; conversion VALU overlaps matrix pipe; ONE barrier
//      per k-tile. Per-acc MFMA order identical -> bit-identical aS.
//   2) lif_scan: R16 verbatim — speculative 8-step dense batches w/ rollback.
typedef __attribute__((ext_vector_type(8))) short short8;
typedef __attribute__((ext_vector_type(4))) float f32x4;

constexpr int BSZ = 256;
constexpr int NRN = 512;
constexpr int KIN = 512;
constexpr int TT  = 500;
constexpr int BM  = 128;   // m-tile
constexpr int BN  = 128;   // n-tile
constexpr int KT  = 32;    // k-tile
constexpr int NBLK = (TT * BSZ / BM) * (NRN / BN);   // 4000
constexpr size_t WS_NEED = (size_t)2 * KIN * NRN * sizeof(unsigned short); // 1 MB
constexpr unsigned long long FULLM = 0xFFFFFFFFFFFFFFFFULL;

__device__ __forceinline__ unsigned short bf16rne(float f) {
    unsigned u = __float_as_uint(f);
    u += 0x7FFFu + ((u >> 16) & 1u);
    return (unsigned short)(u >> 16);
}
__device__ __forceinline__ float bf16f(unsigned short s) {
    return __uint_as_float(((unsigned)s) << 16);
}
// packed RNE bf16 pair: low16 = bf16(a), high16 = bf16(b). Bit-identical to bf16rne.
__device__ __forceinline__ unsigned cvtpk(float a, float b) {
    unsigned r;
    asm("v_cvt_pk_bf16_f32 %0, %1, %2" : "=v"(r) : "v"(a), "v"(b));
    return r;
}

// h1[k][n] -> hi/lo bf16 planes, laid out as the gemm's B-LDS image:
// chunk (kt*4+nb) of 8192 B; byte = ((nl*64+koct*16) ^ (((nl>>1)&3)<<4)) + 2*i
__global__ __launch_bounds__(512)
void split_h(const float* __restrict__ h1,
             unsigned short* __restrict__ wsH,
             unsigned short* __restrict__ wsL)
{
    const int k = blockIdx.x;          // 0..511
    const int n = threadIdx.x;         // 0..511 (coalesced read)
    const float v = h1[(size_t)k * NRN + n];
    const unsigned short h  = bf16rne(v);
    const unsigned short lo = bf16rne(v - bf16f(h));
    const int kt = k >> 5, koct = (k >> 3) & 3, i = k & 7;
    const int nb = n >> 7, nl = n & 127;
    const int byte = (kt * 4 + nb) * 8192 +
                     ((nl * 64 + koct * 16) ^ (((nl >> 1) & 3) << 4)) + i * 2;
    *reinterpret_cast<unsigned short*>((char*)wsH + byte) = h;
    *reinterpret_cast<unsigned short*>((char*)wsL + byte) = lo;
}

// Double-buffered pipelined gemm (requires pre-split ws).
__global__ __launch_bounds__(256)
void lif_gemm_ps(const float* __restrict__ x,
                 const unsigned short* __restrict__ wsH,
                 const unsigned short* __restrict__ wsL,
                 float* __restrict__ out)
{
    // 2 x (A 2x8KB + B 2x8KB) = 64 KB, XOR-swizzled (byte ^= ((row>>1)&3)<<4)
    __shared__ short AhS[2][BM * KT], AlS[2][BM * KT];
    __shared__ short BhS[2][BN * KT], BlS[2][BN * KT];

    const int tid  = threadIdx.x;
    const int l    = tid & 63;
    const int w    = tid >> 6;           // wave 0..3
    const int wm   = (w & 1) * 64;       // wave m-offset
    const int wn   = (w >> 1) * 64;      // wave n-offset
    const int lrow = l & 15;
    const int loct = l >> 4;             // k-octet 0..3

    // XCD-chunked bijective swizzle: 4000 = 8 x 500, 500 % 4 == 0.
    const int nid = (blockIdx.x & 7) * (NBLK / 8) + (blockIdx.x >> 3);
    const size_t m0 = (size_t)(nid >> 2) * BM;
    const int    nb = nid & 3;

    f32x4 acc[4][4];
    #pragma unroll
    for (int i = 0; i < 4; ++i)
        #pragma unroll
        for (int j = 0; j < 4; ++j) acc[i][j] = (f32x4)0.0f;

    // A-stage addressing (each thread owns 4 float4 rows-slots; R16 layout)
    //   u = u4*256+tid, row = u>>3, slot = u&7
    // ---- prologue: stage tile 0 into buffer 0 ----
    {
        const char* sH = (const char*)wsH + nb * 8192;
        const char* sL = (const char*)wsL + nb * 8192;
        *reinterpret_cast<float4*>((char*)BhS[0] + tid * 16) =
            *reinterpret_cast<const float4*>(sH + tid * 16);
        *reinterpret_cast<float4*>((char*)BhS[0] + 4096 + tid * 16) =
            *reinterpret_cast<const float4*>(sH + 4096 + tid * 16);
        *reinterpret_cast<float4*>((char*)BlS[0] + tid * 16) =
            *reinterpret_cast<const float4*>(sL + tid * 16);
        *reinterpret_cast<float4*>((char*)BlS[0] + 4096 + tid * 16) =
            *reinterpret_cast<const float4*>(sL + 4096 + tid * 16);
        #pragma unroll
        for (int u4 = 0; u4 < 4; ++u4) {
            const int u = u4 * 256 + tid;
            const int row = u >> 3, slot = u & 7;
            const float4 xv = *reinterpret_cast<const float4*>(
                x + (m0 + row) * KIN + slot * 4);
            const unsigned h01 = cvtpk(xv.x, xv.y);
            const unsigned h23 = cvtpk(xv.z, xv.w);
            const float r0  = xv.x - __uint_as_float(h01 << 16);
            const float r1v = xv.y - __uint_as_float(h01 & 0xFFFF0000u);
            const float r2  = xv.z - __uint_as_float(h23 << 16);
            const float r3  = xv.w - __uint_as_float(h23 & 0xFFFF0000u);
            const unsigned l01 = cvtpk(r0, r1v);
            const unsigned l23 = cvtpk(r2, r3);
            const unsigned long long hb = (unsigned long long)h01 | ((unsigned long long)h23 << 32);
            const unsigned long long lb = (unsigned long long)l01 | ((unsigned long long)l23 << 32);
            const int byte = (row * 64 + slot * 8) ^ (((row >> 1) & 3) << 4);
            *reinterpret_cast<unsigned long long*>((char*)AhS[0] + byte) = hb;
            *reinterpret_cast<unsigned long long*>((char*)AlS[0] + byte) = lb;
        }
    }
    __syncthreads();

    for (int kt = 0; kt < KIN / KT; ++kt) {
        const int p = kt & 1;

        // ---- issue next tile's global loads (latency hides under MFMA) ----
        float4 xr0, xr1, xr2, xr3, bh0, bh1, bl0, bl1;
        const bool more = (kt + 1 < KIN / KT);
        if (more) {
            const int ktn = kt + 1;
            const char* sH = (const char*)wsH + (ktn * 4 + nb) * 8192;
            const char* sL = (const char*)wsL + (ktn * 4 + nb) * 8192;
            bh0 = *reinterpret_cast<const float4*>(sH + tid * 16);
            bh1 = *reinterpret_cast<const float4*>(sH + 4096 + tid * 16);
            bl0 = *reinterpret_cast<const float4*>(sL + tid * 16);
            bl1 = *reinterpret_cast<const float4*>(sL + 4096 + tid * 16);
            const int u0 = tid, u1 = 256 + tid, u2 = 512 + tid, u3 = 768 + tid;
            xr0 = *reinterpret_cast<const float4*>(
                x + (m0 + (u0 >> 3)) * KIN + ktn * KT + (u0 & 7) * 4);
            xr1 = *reinterpret_cast<const float4*>(
                x + (m0 + (u1 >> 3)) * KIN + ktn * KT + (u1 & 7) * 4);
            xr2 = *reinterpret_cast<const float4*>(
                x + (m0 + (u2 >> 3)) * KIN + ktn * KT + (u2 & 7) * 4);
            xr3 = *reinterpret_cast<const float4*>(
                x + (m0 + (u3 >> 3)) * KIN + ktn * KT + (u3 & 7) * 4);
        }

        // ---- fragment loads from buf[p] (ds_read_b128) ----
        short8 ah[4], al[4], bh[4], bl[4];
        #pragma unroll
        for (int mi = 0; mi < 4; ++mi) {
            const int row  = wm + mi * 16 + lrow;
            const int byte = (row * 64 + loct * 16) ^ (((row >> 1) & 3) << 4);
            ah[mi] = *reinterpret_cast<const short8*>((const char*)AhS[p] + byte);
            al[mi] = *reinterpret_cast<const short8*>((const char*)AlS[p] + byte);
        }
        #pragma unroll
        for (int ni = 0; ni < 4; ++ni) {
            const int nn   = wn + ni * 16 + lrow;
            const int byte = (nn * 64 + loct * 16) ^ (((nn >> 1) & 3) << 4);
            bh[ni] = *reinterpret_cast<const short8*>((const char*)BhS[p] + byte);
            bl[ni] = *reinterpret_cast<const short8*>((const char*)BlS[p] + byte);
        }

        // ---- 48 MFMA: 3-product split (same per-acc order as verified) ----
        __builtin_amdgcn_s_setprio(1);
        #pragma unroll
        for (int mi = 0; mi < 4; ++mi)
            #pragma unroll
            for (int ni = 0; ni < 4; ++ni) {
                acc[mi][ni] = __builtin_amdgcn_mfma_f32_16x16x32_bf16(ah[mi], bh[ni], acc[mi][ni], 0, 0, 0);
                acc[mi][ni] = __builtin_amdgcn_mfma_f32_16x16x32_bf16(ah[mi], bl[ni], acc[mi][ni], 0, 0, 0);
                acc[mi][ni] = __builtin_amdgcn_mfma_f32_16x16x32_bf16(al[mi], bh[ni], acc[mi][ni], 0, 0, 0);
            }
        __builtin_amdgcn_s_setprio(0);

        // ---- convert + write next tile into buf[p^1] (overlaps MFMA) ----
        if (more) {
            const int q = p ^ 1;
            *reinterpret_cast<float4*>((char*)BhS[q] + tid * 16)        = bh0;
            *reinterpret_cast<float4*>((char*)BhS[q] + 4096 + tid * 16) = bh1;
            *reinterpret_cast<float4*>((char*)BlS[q] + tid * 16)        = bl0;
            *reinterpret_cast<float4*>((char*)BlS[q] + 4096 + tid * 16) = bl1;
            const float4 xrs[4] = { xr0, xr1, xr2, xr3 };
            #pragma unroll
            for (int u4 = 0; u4 < 4; ++u4) {
                const int u = u4 * 256 + tid;
                const int row = u >> 3, slot = u & 7;
                const float4 xv = xrs[u4];
                const unsigned h01 = cvtpk(xv.x, xv.y);
                const unsigned h23 = cvtpk(xv.z, xv.w);
                const float r0  = xv.x - __uint_as_float(h01 << 16);
                const float r1v = xv.y - __uint_as_float(h01 & 0xFFFF0000u);
                const float r2  = xv.z - __uint_as_float(h23 << 16);
                const float r3  = xv.w - __uint_as_float(h23 & 0xFFFF0000u);
                const unsigned l01 = cvtpk(r0, r1v);
                const unsigned l23 = cvtpk(r2, r3);
                const unsigned long long hb = (unsigned long long)h01 | ((unsigned long long)h23 << 32);
                const unsigned long long lb = (unsigned long long)l01 | ((unsigned long long)l23 << 32);
                const int byte = (row * 64 + slot * 8) ^ (((row >> 1) & 3) << 4);
                *reinterpret_cast<unsigned long long*>((char*)AhS[q] + byte) = hb;
                *reinterpret_cast<unsigned long long*>((char*)AlS[q] + byte) = lb;
            }
        }
        __syncthreads();   // one barrier per k-tile
    }

    // ---- epilogue: C/D layout col=lane&15, row=(lane>>4)*4+j (m89-verified) ----
    #pragma unroll
    for (int mi = 0; mi < 4; ++mi)
        #pragma unroll
        for (int j = 0; j < 4; ++j) {
            const size_t row = m0 + wm + mi * 16 + loct * 4 + j;
            float* op = out + row * NRN + nb * BN + wn + lrow;
            #pragma unroll
            for (int ni = 0; ni < 4; ++ni)
                op[ni * 16] = acc[mi][ni][j];
        }
}

// Fallback (ws too small): R16 structure, in-kernel B conversion.
__global__ __launch_bounds__(256)
void lif_gemm_fb(const float* __restrict__ x,
                 const float* __restrict__ h1,
                 float* __restrict__ out)
{
    __shared__ short AhS[BM * KT], AlS[BM * KT], BhS[BN * KT], BlS[BN * KT];

    const int tid  = threadIdx.x;
    const int l    = tid & 63;
    const int w    = tid >> 6;
    const int wm   = (w & 1) * 64;
    const int wn   = (w >> 1) * 64;
    const int lrow = l & 15;
    const int loct = l >> 4;

    const int nid = (blockIdx.x & 7) * (NBLK / 8) + (blockIdx.x >> 3);
    const size_t m0 = (size_t)(nid >> 2) * BM;
    const int    n0 = (nid & 3) * BN;

    f32x4 acc[4][4];
    #pragma unroll
    for (int i = 0; i < 4; ++i)
        #pragma unroll
        for (int j = 0; j < 4; ++j) acc[i][j] = (f32x4)0.0f;

    for (int kt = 0; kt < KIN / KT; ++kt) {
        #pragma unroll
        for (int u2 = 0; u2 < 2; ++u2) {
            const int u = u2 * 256 + tid;
            const int nl = u & 127, koct = u >> 7;
            short8 hh, hl;
            #pragma unroll
            for (int i = 0; i < 8; ++i) {
                const float v = h1[(size_t)(kt * KT + koct * 8 + i) * NRN + n0 + nl];
                const unsigned short h = bf16rne(v);
                hh[i] = (short)h;
                hl[i] = (short)bf16rne(v - bf16f(h));
            }
            const int byte = (nl * 64 + koct * 16) ^ (((nl >> 1) & 3) << 4);
            *reinterpret_cast<short8*>((char*)BhS + byte) = hh;
            *reinterpret_cast<short8*>((char*)BlS + byte) = hl;
        }
        #pragma unroll
        for (int u4 = 0; u4 < 4; ++u4) {
            const int u = u4 * 256 + tid;
            const int row = u >> 3, slot = u & 7;
            const float4 xv = *reinterpret_cast<const float4*>(
                x + (m0 + row) * KIN + kt * KT + slot * 4);
            const unsigned h01 = cvtpk(xv.x, xv.y);
            const unsigned h23 = cvtpk(xv.z, xv.w);
            const float r0  = xv.x - __uint_as_float(h01 << 16);
            const float r1v = xv.y - __uint_as_float(h01 & 0xFFFF0000u);
            const float r2  = xv.z - __uint_as_float(h23 << 16);
            const float r3  = xv.w - __uint_as_float(h23 & 0xFFFF0000u);
            const unsigned l01 = cvtpk(r0, r1v);
            const unsigned l23 = cvtpk(r2, r3);
            const unsigned long long hb = (unsigned long long)h01 | ((unsigned long long)h23 << 32);
            const unsigned long long lb = (unsigned long long)l01 | ((unsigned long long)l23 << 32);
            const int byte = (row * 64 + slot * 8) ^ (((row >> 1) & 3) << 4);
            *reinterpret_cast<unsigned long long*>((char*)AhS + byte) = hb;
            *reinterpret_cast<unsigned long long*>((char*)AlS + byte) = lb;
        }
        __syncthreads();

        short8 ah[4], al[4], bh[4], bl[4];
        #pragma unroll
        for (int mi = 0; mi < 4; ++mi) {
            const int row  = wm + mi * 16 + lrow;
            const int byte = (row * 64 + loct * 16) ^ (((row >> 1) & 3) << 4);
            ah[mi] = *reinterpret_cast<const short8*>((const char*)AhS + byte);
            al[mi] = *reinterpret_cast<const short8*>((const char*)AlS + byte);
        }
        #pragma unroll
        for (int ni = 0; ni < 4; ++ni) {
            const int nn   = wn + ni * 16 + lrow;
            const int byte = (nn * 64 + loct * 16) ^ (((nn >> 1) & 3) << 4);
            bh[ni] = *reinterpret_cast<const short8*>((const char*)BhS + byte);
            bl[ni] = *reinterpret_cast<const short8*>((const char*)BlS + byte);
        }

        __builtin_amdgcn_s_setprio(1);
        #pragma unroll
        for (int mi = 0; mi < 4; ++mi)
            #pragma unroll
            for (int ni = 0; ni < 4; ++ni) {
                acc[mi][ni] = __builtin_amdgcn_mfma_f32_16x16x32_bf16(ah[mi], bh[ni], acc[mi][ni], 0, 0, 0);
                acc[mi][ni] = __builtin_amdgcn_mfma_f32_16x16x32_bf16(ah[mi], bl[ni], acc[mi][ni], 0, 0, 0);
                acc[mi][ni] = __builtin_amdgcn_mfma_f32_16x16x32_bf16(al[mi], bh[ni], acc[mi][ni], 0, 0, 0);
            }
        __builtin_amdgcn_s_setprio(0);
        __syncthreads();
    }

    #pragma unroll
    for (int mi = 0; mi < 4; ++mi)
        #pragma unroll
        for (int j = 0; j < 4; ++j) {
            const size_t row = m0 + wm + mi * 16 + loct * 4 + j;
            float* op = out + row * NRN + n0 + wn + lrow;
            #pragma unroll
            for (int ni = 0; ni < 4; ++ni)
                op[ni * 16] = acc[mi][ni][j];
        }
}

__global__ __launch_bounds__(512, 2)
void lif_scan(const float* __restrict__ r1,
              float* __restrict__ out)
{
    __shared__ unsigned long long smask[2][8];   // ping-pong 512-bit spike mask
    __shared__ unsigned long long flg[2];        // per-wave class bytes
    __shared__ unsigned long long vflg;          // batch verdict bytes

    const int n  = threadIdx.x;      // neuron
    const int b  = blockIdx.x;       // batch row
    const int wv = n >> 6;
    const int ln = n & 63;
    const size_t row = (size_t)b * NRN + n;
    constexpr size_t STEP = (size_t)BSZ * NRN;

    if (n < 16) ((unsigned long long*)smask)[n] = 0ULL;
    if (n < 2)  flg[n] = 0ULL;

    // f64 ascending-j column sum of r1 (dense recurrent fast path)
    double csum = 0.0;
    for (int j = 0; j < KIN; ++j)
        csum += (double)r1[(size_t)j * NRN + n];

    double V = 1.0, Is = 0.0, Ir = 0.0, cnt = 0.0;
    const double steady = 0.01 * (double)n;
    constexpr double kS = 0.1, kN = 0.05, DT = 0.001;

    float cur[8], nxt[8];
    #pragma unroll
    for (int i = 0; i < 8; ++i) cur[i] = out[(size_t)i * STEP + row];
    __syncthreads();

#define STD_STEP(T, AREG)                                                     \
    {                                                                         \
        const int t_ = (T);                                                   \
        const int p_ = t_ & 1;                                                \
        const unsigned long long f_ = flg[p_];                                \
        double aR;                                                            \
        if (f_ == FULLM) {                                                    \
            aR = csum;                                                        \
        } else if (f_ == 0ULL) {                                              \
            aR = 0.0;                                                         \
        } else {                                                              \
            aR = 0.0;                                                         \
            _Pragma("unroll")                                                 \
            for (int w = 0; w < 8; ++w) {                                     \
                unsigned long long m_ = smask[p_][w];                         \
                while (m_) {                          /* ascending j */       \
                    const int j = w * 64 + __builtin_ctzll(m_);               \
                    aR += (double)r1[(size_t)j * NRN + n];                    \
                    m_ &= m_ - 1;                                             \
                }                                                             \
            }                                                                 \
        }                                                                     \
        Is = Is - kS * Is + (double)(AREG);            /* gain_syn = 1 */     \
        Ir = Ir - kS * Ir + 0.5 * aR;                  /* gain_syn_rec */     \
        double Vn = V - kN * V + DT * (Is + Ir + steady);                     \
        Vn = fmax(Vn, 0.0);                                                   \
        const bool sp = (Vn - 1.0) > 0.0;                                     \
        cnt = sp ? 2.0 : (cnt - 1.0);                  /* REFR = 2 */         \
        V = sp ? 0.0 : ((cnt <= 0.0) ? Vn : 0.0);                             \
        out[(size_t)t_ * STEP + row] = sp ? 1.0f : 0.0f;                      \
        const unsigned long long bal = __ballot(sp);                          \
        if (ln == 0) {                                                        \
            smask[p_ ^ 1][wv] = bal;                                          \
            const unsigned char fb =                                          \
                (bal == FULLM) ? 0xFFu : ((bal == 0ULL) ? 0x00u : 0x01u);     \
            ((unsigned char*)&flg[p_ ^ 1])[wv] = fb;                          \
        }                                                                     \
        __syncthreads();                                                      \
    }

    for (int t0 = 0; t0 < 496; t0 += 8) {      // 62 batches of 8
        #pragma unroll
        for (int i = 0; i < 8; ++i)
            nxt[i] = (t0 + 8 + i < TT) ? out[(size_t)(t0 + 8 + i) * STEP + row] : 0.0f;

        if (flg[t0 & 1] == FULLM) {
            // ---- speculative dense batch: no barriers, aR = csum each step ----
            const double Vc = V, Isc = Is, Irc = Ir, cc = cnt;
            bool allm = true;
            #pragma unroll
            for (int i = 0; i < 8; ++i) {
                Is = Is - kS * Is + (double)cur[i];
                Ir = Ir - kS * Ir + 0.5 * csum;
                double Vn = V - kN * V + DT * (Is + Ir + steady);
                Vn = fmax(Vn, 0.0);
                const bool sp = (Vn - 1.0) > 0.0;
                allm &= sp;
                cnt = sp ? 2.0 : (cnt - 1.0);
                V = sp ? 0.0 : ((cnt <= 0.0) ? Vn : 0.0);
                out[(size_t)(t0 + i) * STEP + row] = sp ? 1.0f : 0.0f;
            }
            const unsigned long long bal = __ballot(allm);
            if (ln == 0) {
                ((unsigned char*)&vflg)[wv] = (bal == FULLM) ? 0xFFu : 0x00u;
                smask[t0 & 1][wv] = FULLM;
                ((unsigned char*)&flg[t0 & 1])[wv] = 0xFFu;
            }
            __syncthreads();
            if (vflg != FULLM) {
                V = Vc; Is = Isc; Ir = Irc; cnt = cc;
                STD_STEP(t0 + 0, cur[0])
                STD_STEP(t0 + 1, cur[1])
                STD_STEP(t0 + 2, cur[2])
                STD_STEP(t0 + 3, cur[3])
                STD_STEP(t0 + 4, cur[4])
                STD_STEP(t0 + 5, cur[5])
                STD_STEP(t0 + 6, cur[6])
                STD_STEP(t0 + 7, cur[7])
            }
        } else {
            STD_STEP(t0 + 0, cur[0])
            STD_STEP(t0 + 1, cur[1])
            STD_STEP(t0 + 2, cur[2])
            STD_STEP(t0 + 3, cur[3])
            STD_STEP(t0 + 4, cur[4])
            STD_STEP(t0 + 5, cur[5])
            STD_STEP(t0 + 6, cur[6])
            STD_STEP(t0 + 7, cur[7])
        }

        #pragma unroll
        for (int i = 0; i < 8; ++i) cur[i] = nxt[i];
    }

    STD_STEP(496, cur[0])
    STD_STEP(497, cur[1])
    STD_STEP(498, cur[2])
    STD_STEP(499, cur[3])
#undef STD_STEP
}

extern "C" void kernel_launch(void* const* d_in, const int* in_sizes, int n_in,
                              void* d_out, int out_size, void* d_ws, size_t ws_size,
                              hipStream_t stream) {
    const float* x  = (const float*)d_in[0];
    const float* h1 = (const float*)d_in[1];
    const float* r1 = (const float*)d_in[2];
    float* out = (float*)d_out;
    (void)in_sizes; (void)n_in; (void)out_size;

    if (ws_size >= WS_NEED) {
        unsigned short* wsH = (unsigned short*)d_ws;
        unsigned short* wsL = wsH + (size_t)KIN * NRN;
        split_h<<<dim3(KIN), dim3(NRN), 0, stream>>>(h1, wsH, wsL);
        lif_gemm_ps<<<dim3(NBLK), dim3(256), 0, stream>>>(x, wsH, wsL, out);
    } else {
        lif_gemm_fb<<<dim3(NBLK), dim3(256), 0, stream>>>(x, h1, out);
    }
    lif_scan<<<dim3(BSZ), dim3(512), 0, stream>>>(r1, out);
}

// Round 21
// 335.256 us; speedup vs baseline: 1.2441x; 1.0352x over previous
//
#include <hip/hip_runtime.h>

// LIF sim, three-phase (R16 configuration — session optimum, 335.7 µs):
//   0) split_h: pre-split h1 into bf16 hi/lo planes in d_ws ([kt][nb] 8KB
//      chunks == the gemm's swizzled B-LDS image).
//   1) lif_gemm<true>: aS = X @ H via bf16 3-product-split MFMA
//      (xh·hh + xh·hl + xl·hh), f32 accumulate, 128x128 tile, cvt_pk A-split,
//      conflict-free B copy, XCD swizzle, setprio around MFMA cluster.
//   2) lif_scan: speculative 8-step dense batches (aR = csum barrier-free,
//      verified by one ballot+barrier; rollback+replay on failure).
typedef __attribute__((ext_vector_type(8))) short short8;
typedef __attribute__((ext_vector_type(4))) float f32x4;

constexpr int BSZ = 256;
constexpr int NRN = 512;
constexpr int KIN = 512;
constexpr int TT  = 500;
constexpr int BM  = 128;   // m-tile
constexpr int BN  = 128;   // n-tile
constexpr int KT  = 32;    // k-tile
constexpr int NBLK = (TT * BSZ / BM) * (NRN / BN);   // 4000
constexpr size_t WS_NEED = (size_t)2 * KIN * NRN * sizeof(unsigned short); // 1 MB
constexpr unsigned long long FULLM = 0xFFFFFFFFFFFFFFFFULL;

__device__ __forceinline__ unsigned short bf16rne(float f) {
    unsigned u = __float_as_uint(f);
    u += 0x7FFFu + ((u >> 16) & 1u);
    return (unsigned short)(u >> 16);
}
__device__ __forceinline__ float bf16f(unsigned short s) {
    return __uint_as_float(((unsigned)s) << 16);
}
// packed RNE bf16 pair: low16 = bf16(a), high16 = bf16(b). Bit-identical to bf16rne.
__device__ __forceinline__ unsigned cvtpk(float a, float b) {
    unsigned r;
    asm("v_cvt_pk_bf16_f32 %0, %1, %2" : "=v"(r) : "v"(a), "v"(b));
    return r;
}

// h1[k][n] -> hi/lo bf16 planes, laid out as the gemm's B-LDS image:
// chunk (kt*4+nb) of 8192 B; byte = ((nl*64+koct*16) ^ (((nl>>1)&3)<<4)) + 2*i
__global__ __launch_bounds__(512)
void split_h(const float* __restrict__ h1,
             unsigned short* __restrict__ wsH,
             unsigned short* __restrict__ wsL)
{
    const int k = blockIdx.x;          // 0..511
    const int n = threadIdx.x;         // 0..511 (coalesced read)
    const float v = h1[(size_t)k * NRN + n];
    const unsigned short h  = bf16rne(v);
    const unsigned short lo = bf16rne(v - bf16f(h));
    const int kt = k >> 5, koct = (k >> 3) & 3, i = k & 7;
    const int nb = n >> 7, nl = n & 127;
    const int byte = (kt * 4 + nb) * 8192 +
                     ((nl * 64 + koct * 16) ^ (((nl >> 1) & 3) << 4)) + i * 2;
    *reinterpret_cast<unsigned short*>((char*)wsH + byte) = h;
    *reinterpret_cast<unsigned short*>((char*)wsL + byte) = lo;
}

template<bool PS>
__global__ __launch_bounds__(256)
void lif_gemm(const float* __restrict__ x,
              const float* __restrict__ h1,
              const unsigned short* __restrict__ wsH,
              const unsigned short* __restrict__ wsL,
              float* __restrict__ out)
{
    // bf16 tiles, XOR-swizzled (byte ^= ((row>>1)&3)<<4): 4 x 8 KB = 32 KB
    __shared__ short AhS[BM * KT], AlS[BM * KT], BhS[BN * KT], BlS[BN * KT];

    const int tid  = threadIdx.x;
    const int l    = tid & 63;
    const int w    = tid >> 6;           // wave 0..3
    const int wm   = (w & 1) * 64;       // wave m-offset
    const int wn   = (w >> 1) * 64;      // wave n-offset
    const int lrow = l & 15;
    const int loct = l >> 4;             // k-octet 0..3

    // XCD-chunked bijective swizzle: 4000 = 8 x 500, 500 % 4 == 0 so the
    // 4 n-blocks of each m-tile stay inside one XCD's chunk (shared L2).
    const int nid = (blockIdx.x & 7) * (NBLK / 8) + (blockIdx.x >> 3);
    const size_t m0 = (size_t)(nid >> 2) * BM;
    const int    nb = nid & 3;
    const int    n0 = nb * BN;

    f32x4 acc[4][4];
    #pragma unroll
    for (int i = 0; i < 4; ++i)
        #pragma unroll
        for (int j = 0; j < 4; ++j) acc[i][j] = (f32x4)0.0f;

    for (int kt = 0; kt < KIN / KT; ++kt) {
        // ---- stage B (independent loads issue first, overlap A conversion) ----
        if (PS) {
            // linear conflict-free copy: 16B/lane consecutive
            const float4* sH = reinterpret_cast<const float4*>(
                (const char*)wsH + (kt * 4 + nb) * 8192);
            const float4* sL = reinterpret_cast<const float4*>(
                (const char*)wsL + (kt * 4 + nb) * 8192);
            float4* dH = reinterpret_cast<float4*>(BhS);
            float4* dL = reinterpret_cast<float4*>(BlS);
            dH[tid]       = sH[tid];
            dH[256 + tid] = sH[256 + tid];
            dL[tid]       = sL[tid];
            dL[256 + tid] = sL[256 + tid];
        } else {
            #pragma unroll
            for (int u2 = 0; u2 < 2; ++u2) {
                const int u = u2 * 256 + tid;          // 0..511
                const int nl = u & 127, koct = u >> 7; // n-local, k-octet
                short8 hh, hl;
                #pragma unroll
                for (int i = 0; i < 8; ++i) {          // coalesced across nl
                    const float v = h1[(size_t)(kt * KT + koct * 8 + i) * NRN + n0 + nl];
                    const unsigned short h = bf16rne(v);
                    hh[i] = (short)h;
                    hl[i] = (short)bf16rne(v - bf16f(h));
                }
                const int byte = (nl * 64 + koct * 16) ^ (((nl >> 1) & 3) << 4);
                *reinterpret_cast<short8*>((char*)BhS + byte) = hh;
                *reinterpret_cast<short8*>((char*)BlS + byte) = hl;
            }
        }
        // ---- stage A: x[m0..m0+128][kt*32..+32] -> bf16 split via cvt_pk ----
        #pragma unroll
        for (int u4 = 0; u4 < 4; ++u4) {
            const int u = u4 * 256 + tid;         // 0..1023
            const int row = u >> 3, slot = u & 7; // row 0..127, float4 slot 0..7
            const float4 xv = *reinterpret_cast<const float4*>(
                x + (m0 + row) * KIN + kt * KT + slot * 4);
            // hi plane (RNE, bit-identical to bf16rne)
            const unsigned h01 = cvtpk(xv.x, xv.y);
            const unsigned h23 = cvtpk(xv.z, xv.w);
            // residuals: bf16f(lo16)=bits<<16, bf16f(hi16)=bits&0xFFFF0000
            const float r0  = xv.x - __uint_as_float(h01 << 16);
            const float r1v = xv.y - __uint_as_float(h01 & 0xFFFF0000u);
            const float r2  = xv.z - __uint_as_float(h23 << 16);
            const float r3  = xv.w - __uint_as_float(h23 & 0xFFFF0000u);
            const unsigned l01 = cvtpk(r0, r1v);
            const unsigned l23 = cvtpk(r2, r3);
            const unsigned long long hb = (unsigned long long)h01 | ((unsigned long long)h23 << 32);
            const unsigned long long lb = (unsigned long long)l01 | ((unsigned long long)l23 << 32);
            const int byte = (row * 64 + slot * 8) ^ (((row >> 1) & 3) << 4);
            *reinterpret_cast<unsigned long long*>((char*)AhS + byte) = hb;
            *reinterpret_cast<unsigned long long*>((char*)AlS + byte) = lb;
        }
        __syncthreads();

        // ---- fragment loads (ds_read_b128) ----
        short8 ah[4], al[4], bh[4], bl[4];
        #pragma unroll
        for (int mi = 0; mi < 4; ++mi) {
            const int row  = wm + mi * 16 + lrow;
            const int byte = (row * 64 + loct * 16) ^ (((row >> 1) & 3) << 4);
            ah[mi] = *reinterpret_cast<const short8*>((const char*)AhS + byte);
            al[mi] = *reinterpret_cast<const short8*>((const char*)AlS + byte);
        }
        #pragma unroll
        for (int ni = 0; ni < 4; ++ni) {
            const int nn   = wn + ni * 16 + lrow;
            const int byte = (nn * 64 + loct * 16) ^ (((nn >> 1) & 3) << 4);
            bh[ni] = *reinterpret_cast<const short8*>((const char*)BhS + byte);
            bl[ni] = *reinterpret_cast<const short8*>((const char*)BlS + byte);
        }

        // ---- 48 MFMA: 3-product split (xl·hl dropped, ~1e-4 class) ----
        __builtin_amdgcn_s_setprio(1);
        #pragma unroll
        for (int mi = 0; mi < 4; ++mi)
            #pragma unroll
            for (int ni = 0; ni < 4; ++ni) {
                acc[mi][ni] = __builtin_amdgcn_mfma_f32_16x16x32_bf16(ah[mi], bh[ni], acc[mi][ni], 0, 0, 0);
                acc[mi][ni] = __builtin_amdgcn_mfma_f32_16x16x32_bf16(ah[mi], bl[ni], acc[mi][ni], 0, 0, 0);
                acc[mi][ni] = __builtin_amdgcn_mfma_f32_16x16x32_bf16(al[mi], bh[ni], acc[mi][ni], 0, 0, 0);
            }
        __builtin_amdgcn_s_setprio(0);
        __syncthreads();
    }

    // ---- epilogue: C/D layout col=lane&15, row=(lane>>4)*4+j (m89-verified) ----
    #pragma unroll
    for (int mi = 0; mi < 4; ++mi)
        #pragma unroll
        for (int j = 0; j < 4; ++j) {
            const size_t row = m0 + wm + mi * 16 + loct * 4 + j;
            float* op = out + row * NRN + n0 + wn + lrow;
            #pragma unroll
            for (int ni = 0; ni < 4; ++ni)
                op[ni * 16] = acc[mi][ni][j];
        }
}

__global__ __launch_bounds__(512, 2)
void lif_scan(const float* __restrict__ r1,
              float* __restrict__ out)
{
    __shared__ unsigned long long smask[2][8];   // ping-pong 512-bit spike mask
    __shared__ unsigned long long flg[2];        // per-wave class bytes
    __shared__ unsigned long long vflg;          // batch verdict bytes

    const int n  = threadIdx.x;      // neuron
    const int b  = blockIdx.x;       // batch row
    const int wv = n >> 6;
    const int ln = n & 63;
    const size_t row = (size_t)b * NRN + n;
    constexpr size_t STEP = (size_t)BSZ * NRN;

    if (n < 16) ((unsigned long long*)smask)[n] = 0ULL;
    if (n < 2)  flg[n] = 0ULL;

    // f64 ascending-j column sum of r1 (dense recurrent fast path)
    double csum = 0.0;
    for (int j = 0; j < KIN; ++j)
        csum += (double)r1[(size_t)j * NRN + n];

    double V = 1.0, Is = 0.0, Ir = 0.0, cnt = 0.0;
    const double steady = 0.01 * (double)n;
    constexpr double kS = 0.1, kN = 0.05, DT = 0.001;

    float cur[8], nxt[8];
    #pragma unroll
    for (int i = 0; i < 8; ++i) cur[i] = out[(size_t)i * STEP + row];
    __syncthreads();

#define STD_STEP(T, AREG)                                                     \
    {                                                                         \
        const int t_ = (T);                                                   \
        const int p_ = t_ & 1;                                                \
        const unsigned long long f_ = flg[p_];                                \
        double aR;                                                            \
        if (f_ == FULLM) {                                                    \
            aR = csum;                                                        \
        } else if (f_ == 0ULL) {                                              \
            aR = 0.0;                                                         \
        } else {                                                              \
            aR = 0.0;                                                         \
            _Pragma("unroll")                                                 \
            for (int w = 0; w < 8; ++w) {                                     \
                unsigned long long m_ = smask[p_][w];                         \
                while (m_) {                          /* ascending j */       \
                    const int j = w * 64 + __builtin_ctzll(m_);               \
                    aR += (double)r1[(size_t)j * NRN + n];                    \
                    m_ &= m_ - 1;                                             \
                }                                                             \
            }                                                                 \
        }                                                                     \
        Is = Is - kS * Is + (double)(AREG);            /* gain_syn = 1 */     \
        Ir = Ir - kS * Ir + 0.5 * aR;                  /* gain_syn_rec */     \
        double Vn = V - kN * V + DT * (Is + Ir + steady);                     \
        Vn = fmax(Vn, 0.0);                                                   \
        const bool sp = (Vn - 1.0) > 0.0;                                     \
        cnt = sp ? 2.0 : (cnt - 1.0);                  /* REFR = 2 */         \
        V = sp ? 0.0 : ((cnt <= 0.0) ? Vn : 0.0);                             \
        out[(size_t)t_ * STEP + row] = sp ? 1.0f : 0.0f;                      \
        const unsigned long long bal = __ballot(sp);                          \
        if (ln == 0) {                                                        \
            smask[p_ ^ 1][wv] = bal;                                          \
            const unsigned char fb =                                          \
                (bal == FULLM) ? 0xFFu : ((bal == 0ULL) ? 0x00u : 0x01u);     \
            ((unsigned char*)&flg[p_ ^ 1])[wv] = fb;                          \
        }                                                                     \
        __syncthreads();                                                      \
    }

    for (int t0 = 0; t0 < 496; t0 += 8) {      // 62 batches of 8
        #pragma unroll
        for (int i = 0; i < 8; ++i)
            nxt[i] = (t0 + 8 + i < TT) ? out[(size_t)(t0 + 8 + i) * STEP + row] : 0.0f;

        if (flg[t0 & 1] == FULLM) {
            // ---- speculative dense batch: no barriers, aR = csum each step ----
            const double Vc = V, Isc = Is, Irc = Ir, cc = cnt;
            bool allm = true;
            #pragma unroll
            for (int i = 0; i < 8; ++i) {
                Is = Is - kS * Is + (double)cur[i];
                Ir = Ir - kS * Ir + 0.5 * csum;
                double Vn = V - kN * V + DT * (Is + Ir + steady);
                Vn = fmax(Vn, 0.0);
                const bool sp = (Vn - 1.0) > 0.0;
                allm &= sp;
                cnt = sp ? 2.0 : (cnt - 1.0);
                V = sp ? 0.0 : ((cnt <= 0.0) ? Vn : 0.0);
                out[(size_t)(t0 + i) * STEP + row] = sp ? 1.0f : 0.0f;
            }
            const unsigned long long bal = __ballot(allm);
            if (ln == 0) {
                ((unsigned char*)&vflg)[wv] = (bal == FULLM) ? 0xFFu : 0x00u;
                smask[t0 & 1][wv] = FULLM;
                ((unsigned char*)&flg[t0 & 1])[wv] = 0xFFu;
            }
            __syncthreads();
            if (vflg != FULLM) {
                V = Vc; Is = Isc; Ir = Irc; cnt = cc;
                STD_STEP(t0 + 0, cur[0])
                STD_STEP(t0 + 1, cur[1])
                STD_STEP(t0 + 2, cur[2])
                STD_STEP(t0 + 3, cur[3])
                STD_STEP(t0 + 4, cur[4])
                STD_STEP(t0 + 5, cur[5])
                STD_STEP(t0 + 6, cur[6])
                STD_STEP(t0 + 7, cur[7])
            }
        } else {
            STD_STEP(t0 + 0, cur[0])
            STD_STEP(t0 + 1, cur[1])
            STD_STEP(t0 + 2, cur[2])
            STD_STEP(t0 + 3, cur[3])
            STD_STEP(t0 + 4, cur[4])
            STD_STEP(t0 + 5, cur[5])
            STD_STEP(t0 + 6, cur[6])
            STD_STEP(t0 + 7, cur[7])
        }

        #pragma unroll
        for (int i = 0; i < 8; ++i) cur[i] = nxt[i];
    }

    STD_STEP(496, cur[0])
    STD_STEP(497, cur[1])
    STD_STEP(498, cur[2])
    STD_STEP(499, cur[3])
#undef STD_STEP
}

extern "C" void kernel_launch(void* const* d_in, const int* in_sizes, int n_in,
                              void* d_out, int out_size, void* d_ws, size_t ws_size,
                              hipStream_t stream) {
    const float* x  = (const float*)d_in[0];
    const float* h1 = (const float*)d_in[1];
    const float* r1 = (const float*)d_in[2];
    float* out = (float*)d_out;
    (void)in_sizes; (void)n_in; (void)out_size;

    if (ws_size >= WS_NEED) {
        unsigned short* wsH = (unsigned short*)d_ws;
        unsigned short* wsL = wsH + (size_t)KIN * NRN;
        split_h<<<dim3(KIN), dim3(NRN), 0, stream>>>(h1, wsH, wsL);
        lif_gemm<true><<<dim3(NBLK), dim3(256), 0, stream>>>(x, h1, wsH, wsL, out);
    } else {
        lif_gemm<false><<<dim3(NBLK), dim3(256), 0, stream>>>(x, h1, nullptr, nullptr, out);
    }
    lif_scan<<<dim3(BSZ), dim3(512), 0, stream>>>(r1, out);
}